// Round 9
// baseline (361.861 us; speedup 1.0000x reference)
//
#include <hip/hip_runtime.h>
#include <hip/hip_bf16.h>

// JetGNN: 2-layer SAGEConv(mean) + ReLU + global_mean_pool + Linear(64->2)
// R1-R21: scan/CSR/pool/agg/MFMA ladder (see git log). 355.7us R21.
// R22-R28: fusion arc. Gather rate pinned at ~1.9-2.0 TB/s across occupancy
//      19->37% and txn-shape 2x => phase-dilution: waves in MFMA/flush/barrier
//      phases don't issue gather loads; split agg (all waves gather, no
//      barrier) measured 3.46 TB/s at same FETCH.
// R29: pool de-atomicized (LDS accumulate + boundary-only global atomics):
//      WRITE 21.9->1.76MB, fused2 115->99us. Total 344.6.
// R30: layer 2 re-split: agg_bf16<64> (R21 verbatim, 61.4us measured) +
//      mfma_dense<64,POOL> = R0 staging + B-direct (R24) + LDS pool (R29).
//      Layer 1 stays fused (xb is L2/L3-resident; fused1 < agg1+mfma1).

#define WS_ALIGN 64
#define EPB 4096          // edges per block in bucket_scatter (256 thr x 16)
#define BSHIFT 8          // 256 nodes per bucket
#define BNODES 256
#define BCAP 6144         // region capacity (mean 4096, sd 64, +32 sigma)
#define MAXNB 1024

typedef short bf16x8 __attribute__((ext_vector_type(8)));
typedef float f32x4 __attribute__((ext_vector_type(4)));

__device__ inline unsigned short f2bf(float f) {   // RNE f32->bf16 (finite inputs)
    unsigned u = __float_as_uint(f);
    return (unsigned short)((u + 0x7fffu + ((u >> 16) & 1u)) >> 16);
}

__device__ inline void acc8(const uint4 u, float* a) {  // 8 bf16 -> fp32 accumulate
    a[0] += __uint_as_float(u.x << 16);
    a[1] += __uint_as_float(u.x & 0xffff0000u);
    a[2] += __uint_as_float(u.y << 16);
    a[3] += __uint_as_float(u.y & 0xffff0000u);
    a[4] += __uint_as_float(u.z << 16);
    a[5] += __uint_as_float(u.z & 0xffff0000u);
    a[6] += __uint_as_float(u.w << 16);
    a[7] += __uint_as_float(u.w & 0xffff0000u);
}

// ---------- prep: x->bf16 cvt + weight prepack + cursors + pool zero ----------

__global__ void prep_kernel(const float* __restrict__ x, unsigned short* __restrict__ xb,
                            const float* __restrict__ W1_l, const float* __restrict__ W1_r,
                            const float* __restrict__ W2_l, const float* __restrict__ W2_r,
                            unsigned short* __restrict__ whi1, unsigned short* __restrict__ whi2,
                            int* __restrict__ bucketCursor, float* __restrict__ pool,
                            int N, int NB, int G, int total4) {
    const int gid = blockIdx.x * blockDim.x + threadIdx.x;
    if (gid < total4) {
        const float4 v = reinterpret_cast<const float4*>(x)[gid];
        ushort4 o;
        o.x = f2bf(v.x); o.y = f2bf(v.y); o.z = f2bf(v.z); o.w = f2bf(v.w);
        reinterpret_cast<ushort4*>(xb)[gid] = o;
    }
    if (gid < NB) bucketCursor[gid] = gid * BCAP;
    if (gid < G * 64) pool[gid] = 0.0f;     // consumed only by mfma2 (later launch)
    if (gid < 64 * 64) {        // whi1: rows [o][k], K=64
        const int o = gid >> 6, k = gid & 63;
        const float v = (k < 32) ? W1_l[o * 32 + k] : W1_r[o * 32 + (k - 32)];
        whi1[gid] = f2bf(v);
    }
    if (gid < 64 * 128) {       // whi2: rows [o][k], K=128
        const int o = gid >> 7, k = gid & 127;
        const float v = (k < 64) ? W2_l[o * 64 + k] : W2_r[o * 64 + (k - 64)];
        whi2[gid] = f2bf(v);
    }
}

// ---------- bucket scatter: edges -> fixed-capacity bucket regions ----------

__global__ __launch_bounds__(256) void bucket_scatter_kernel(const int* __restrict__ src,
                                                             const int* __restrict__ dst,
                                                             int* __restrict__ bucketCursor,
                                                             unsigned* __restrict__ bucketData,
                                                             int E, int NB) {
    __shared__ int hist[MAXNB];
    __shared__ int cur[MAXNB];
    const int t = threadIdx.x;
    for (int i = t; i < MAXNB; i += 256) hist[i] = 0;
    __syncthreads();
    const int eBase = blockIdx.x * EPB + t;
    int s[16], b[16], dl[16];
#pragma unroll
    for (int j = 0; j < 16; ++j) {
        int e = eBase + j * 256;
        if (e < E) {
            int d = dst[e];
            s[j]  = src[e];
            b[j]  = d >> BSHIFT;
            dl[j] = d & (BNODES - 1);
            atomicAdd(&hist[b[j]], 1);
        } else {
            b[j] = -1;
        }
    }
    __syncthreads();
    for (int bb = t; bb < NB; bb += 256)
        if (hist[bb] > 0) cur[bb] = atomicAdd(&bucketCursor[bb], hist[bb]);
    __syncthreads();
#pragma unroll
    for (int j = 0; j < 16; ++j) {
        if (b[j] >= 0) {
            int pos = atomicAdd(&cur[b[j]], 1);
            if (pos < (b[j] + 1) * BCAP)     // overflow guard (statistically never)
                bucketData[pos] = ((unsigned)s[j] << BSHIFT) | (unsigned)dl[j];
        }
    }
}

// one block per bucket (256 nodes): LDS deg hist over its region -> scan ->
// offs/offe; scatter pass into the region (dense, single-XCD write-back)
__global__ __launch_bounds__(256) void csr_build_kernel(const unsigned* __restrict__ bucketData,
                                                        const int* __restrict__ bucketCursor,
                                                        int* __restrict__ offs,
                                                        int* __restrict__ offe,
                                                        int* __restrict__ csr_src,
                                                        int N) {
    __shared__ int cnt[BNODES];
    __shared__ int sscan[BNODES];
    __shared__ int cur[BNODES];
    const int t   = threadIdx.x;
    const int bkt = blockIdx.x;
    const int nodeBase = bkt << BSHIFT;
    const int regionBase = bkt * BCAP;
    const int count = min(bucketCursor[bkt] - regionBase, BCAP);
    cnt[t] = 0;
    __syncthreads();
    for (int k = regionBase + t; k < regionBase + count; k += 256)
        atomicAdd(&cnt[bucketData[k] & (BNODES - 1)], 1);
    __syncthreads();
    int v0 = cnt[t];
    sscan[t] = v0;
    __syncthreads();
    for (int off = 1; off < 256; off <<= 1) {
        int v = (t >= off) ? sscan[t - off] : 0;
        __syncthreads();
        sscan[t] += v;
        __syncthreads();
    }
    const int excl = sscan[t] - v0;
    cur[t] = excl;
    const int node = nodeBase + t;
    if (node < N) {
        offs[node] = regionBase + excl;
        offe[node] = regionBase + excl + v0;
    }
    __syncthreads();
    for (int k = regionBase + t; k < regionBase + count; k += 256) {
        const unsigned v = bucketData[k];
        const int d = (int)(v & (BNODES - 1));
        const int pos = regionBase + atomicAdd(&cur[d], 1);
        csr_src[pos] = (int)(v >> BSHIFT);
    }
}

// ---------- mean aggregation bf16 -> bf16 (fp32 accumulate, 8-deep) ----------
// R21-measured 61.4us @ D=64: TPN threads/node, 1 uint4/edge, no barriers.

template <int D>
__global__ void agg_bf16_kernel(const unsigned short* __restrict__ featb,
                                const int* __restrict__ csr_src,
                                const int* __restrict__ offs,
                                const int* __restrict__ offe,
                                unsigned short* __restrict__ aggb, int N) {
    constexpr int TPN = D / 8;
    int tid  = blockIdx.x * blockDim.x + threadIdx.x;
    int node = tid / TPN;
    int part = tid % TPN;
    if (node >= N) return;
    const int beg = offs[node];
    const int end = offe[node];
    const uint4* base = reinterpret_cast<const uint4*>(featb);
    float a[8] = {0.f, 0.f, 0.f, 0.f, 0.f, 0.f, 0.f, 0.f};
    int k = beg;
    for (; k + 8 <= end; k += 8) {
        int s[8];
#pragma unroll
        for (int j = 0; j < 8; ++j) s[j] = csr_src[k + j];
        uint4 u[8];
#pragma unroll
        for (int j = 0; j < 8; ++j) u[j] = base[(size_t)s[j] * TPN + part];
#pragma unroll
        for (int j = 0; j < 8; ++j) acc8(u[j], a);
    }
    for (; k + 4 <= end; k += 4) {
        const int s0 = csr_src[k + 0];
        const int s1 = csr_src[k + 1];
        const int s2 = csr_src[k + 2];
        const int s3 = csr_src[k + 3];
        const uint4 u0 = base[(size_t)s0 * TPN + part];
        const uint4 u1 = base[(size_t)s1 * TPN + part];
        const uint4 u2 = base[(size_t)s2 * TPN + part];
        const uint4 u3 = base[(size_t)s3 * TPN + part];
        acc8(u0, a); acc8(u1, a); acc8(u2, a); acc8(u3, a);
    }
    for (; k < end; ++k) {
        const uint4 u = base[(size_t)csr_src[k] * TPN + part];
        acc8(u, a);
    }
    const float inv = 1.0f / fmaxf((float)(end - beg), 1.0f);
    ushort4 lo, hi;
    lo.x = f2bf(a[0] * inv); lo.y = f2bf(a[1] * inv);
    lo.z = f2bf(a[2] * inv); lo.w = f2bf(a[3] * inv);
    hi.x = f2bf(a[4] * inv); hi.y = f2bf(a[5] * inv);
    hi.z = f2bf(a[6] * inv); hi.w = f2bf(a[7] * inv);
    unsigned short* dstp = aggb + (size_t)node * D + part * 8;
    *reinterpret_cast<ushort4*>(dstp)     = lo;
    *reinterpret_cast<ushort4*>(dstp + 4) = hi;
}

// ---------- dense MFMA 16x16x32 bf16: A staged (aggb|xinb), B direct ----------
// Pool: LDS accumulate + boundary-only global atomics (R29).

template <int DIN, bool POOL>
__launch_bounds__(256)
__global__ void mfma_dense_kernel(const unsigned short* __restrict__ aggb,
                                  const unsigned short* __restrict__ xinb,
                                  const unsigned short* __restrict__ whi,
                                  const float* __restrict__ bias,
                                  unsigned short* __restrict__ houtb,
                                  const int* __restrict__ batch,
                                  float* __restrict__ pool_sum,
                                  int N, int nSteps) {
    constexpr int K   = 2 * DIN;      // 64 / 128
    constexpr int STR = K + 8;        // 72 / 136 ushorts, rows 16B-aligned
    constexpr int D8  = DIN / 8;
    __shared__ unsigned short A_s[64 * STR];
    __shared__ float poolLds[POOL ? 64 * 65 : 1];   // [graph-row][ch]
    const int tid = threadIdx.x;
    const int nodeBase = blockIdx.x * 64;

    if (POOL) {
        for (int i = tid; i < 64 * 65; i += 256) poolLds[i] = 0.0f;
    }
    // A: aggb into k [0, DIN), xinb into k [DIN, 2*DIN)
    for (int i = tid; i < 64 * D8 * 2; i += 256) {
        const int half = i / (64 * D8);
        const int j = i % (64 * D8);
        const int node = j / D8, q = j % D8;
        const int n = min(nodeBase + node, N - 1);
        const unsigned short* srcp = half ? xinb : aggb;
        const uint4 u = *reinterpret_cast<const uint4*>(srcp + (size_t)n * DIN + q * 8);
        *reinterpret_cast<uint4*>(&A_s[node * STR + half * DIN + q * 8]) = u;
    }
    __syncthreads();

    const int lane = tid & 63;
    const int wave = tid >> 6;
    const int lr = lane & 15;        // A: m (node); B: n (out); D: col (out)
    const int q  = lane >> 4;        // frag k-quad; D row group
    f32x4 acc[4];
#pragma unroll
    for (int t = 0; t < 4; ++t) {
        const float b = bias[t * 16 + lr];
        acc[t] = (f32x4){b, b, b, b};
    }
    const unsigned short* Arow = &A_s[(wave * 16 + lr) * STR + q * 8];
    const unsigned short* Brow = whi + (size_t)lr * K + q * 8;   // + t*16*K + s*32
    for (int s = 0; s < nSteps; ++s) {    // runtime: no full unroll (R11)
        const bf16x8 af = *reinterpret_cast<const bf16x8*>(Arow + s * 32);
#pragma unroll
        for (int t = 0; t < 4; ++t) {
            const bf16x8 bh = *reinterpret_cast<const bf16x8*>(
                Brow + (size_t)t * 16 * K + s * 32);
            acc[t] = __builtin_amdgcn_mfma_f32_16x16x32_bf16(af, bh, acc[t], 0, 0, 0);
        }
    }

    // D layout: row(node local 16) = q*4 + reg, col(out) = t*16 + lr
    if (POOL) {
        const int g0 = batch[nodeBase];
        float ag[4] = {0.f, 0.f, 0.f, 0.f};
        int gcur = -1;
        for (int reg = 0; reg < 4; ++reg) {
            const int n = nodeBase + wave * 16 + q * 4 + reg;
            if (n >= N) break;
            const int g = batch[n];              // sorted
            if (g != gcur) {
                if (gcur >= 0) {
#pragma unroll
                    for (int t = 0; t < 4; ++t)
                        atomicAdd(&poolLds[(gcur - g0) * 65 + t * 16 + lr], ag[t]);
                }
                gcur = g;
                ag[0] = ag[1] = ag[2] = ag[3] = 0.f;
            }
#pragma unroll
            for (int t = 0; t < 4; ++t)
                ag[t] += fmaxf(acc[t][reg], 0.0f);
        }
        if (gcur >= 0) {
#pragma unroll
            for (int t = 0; t < 4; ++t)
                atomicAdd(&poolLds[(gcur - g0) * 65 + t * 16 + lr], ag[t]);
        }
        __syncthreads();
        // interior graphs wholly inside this block -> plain store; boundary
        // rows (r==0, r==S-1) shared with neighbors -> global atomicAdd.
        const int glast = batch[min(nodeBase + 63, N - 1)];
        const int S = glast - g0 + 1;            // <= 64
        for (int i = tid; i < S * 64; i += 256) {
            const int r = i >> 6, c = i & 63;
            const float v = poolLds[r * 65 + c];
            float* dstp = &pool_sum[(size_t)(g0 + r) * 64 + c];
            if (r == 0 || r == S - 1) atomicAdd(dstp, v);
            else *dstp = v;
        }
    } else {
        for (int reg = 0; reg < 4; ++reg) {
            const int n = nodeBase + wave * 16 + q * 4 + reg;
            if (n >= N) break;
#pragma unroll
            for (int t = 0; t < 4; ++t)
                houtb[(size_t)n * 64 + t * 16 + lr] = f2bf(fmaxf(acc[t][reg], 0.0f));
        }
    }
}

// ---------- fused gather-mean + MFMA (layer 1 only: xb is L2/L3-hot) ----------

template <int DIN, bool POOL>
__launch_bounds__(256)
__global__ void fused_agg_mfma_kernel(const unsigned short* __restrict__ featb,
                                      const unsigned short* __restrict__ whi,
                                      const float* __restrict__ bias,
                                      const int* __restrict__ csr_src,
                                      const int* __restrict__ offs,
                                      const int* __restrict__ offe,
                                      unsigned short* __restrict__ houtb,
                                      const int* __restrict__ batch,
                                      float* __restrict__ pool_sum,
                                      int N, int nSteps) {
    constexpr int K     = 2 * DIN;    // 64
    constexpr int STR   = K + 8;      // 72
    constexpr int D8    = DIN / 8;    // 4
    constexpr int NPN   = 256 / D8;   // 64
    constexpr int NPASS = 64 / NPN;   // 1
    __shared__ unsigned short A_s[64 * STR];
    const int tid = threadIdx.x;
    const int nodeBase = blockIdx.x * 64;

    // self features into k [DIN, 2*DIN)
    for (int i = tid; i < 64 * D8; i += 256) {
        const int node = i / D8, q = i % D8;
        const int n = min(nodeBase + node, N - 1);
        const uint4 u = *reinterpret_cast<const uint4*>(featb + (size_t)n * DIN + q * 8);
        *reinterpret_cast<uint4*>(&A_s[node * STR + DIN + q * 8]) = u;
    }

    // gather-mean into k [0, DIN): D8 threads/node, 1 uint4/edge
    {
        const int part = tid % D8;
        const uint4* base = reinterpret_cast<const uint4*>(featb);
#pragma unroll
        for (int pass = 0; pass < NPASS; ++pass) {
            const int node = pass * NPN + tid / D8;
            const int n = nodeBase + node;
            unsigned short* dp = &A_s[node * STR + part * 8];
            if (n < N) {
                const int beg = offs[n];
                const int end = offe[n];
                float a[8] = {0.f, 0.f, 0.f, 0.f, 0.f, 0.f, 0.f, 0.f};
                int k = beg;
                for (; k + 8 <= end; k += 8) {       // 8 uint4 in flight
                    int s[8];
#pragma unroll
                    for (int j = 0; j < 8; ++j) s[j] = csr_src[k + j];
                    uint4 u[8];
#pragma unroll
                    for (int j = 0; j < 8; ++j) u[j] = base[(size_t)s[j] * D8 + part];
#pragma unroll
                    for (int j = 0; j < 8; ++j) acc8(u[j], a);
                }
                for (; k + 4 <= end; k += 4) {
                    const int s0 = csr_src[k + 0];
                    const int s1 = csr_src[k + 1];
                    const int s2 = csr_src[k + 2];
                    const int s3 = csr_src[k + 3];
                    const uint4 u0 = base[(size_t)s0 * D8 + part];
                    const uint4 u1 = base[(size_t)s1 * D8 + part];
                    const uint4 u2 = base[(size_t)s2 * D8 + part];
                    const uint4 u3 = base[(size_t)s3 * D8 + part];
                    acc8(u0, a); acc8(u1, a); acc8(u2, a); acc8(u3, a);
                }
                for (; k < end; ++k) {
                    const uint4 u = base[(size_t)csr_src[k] * D8 + part];
                    acc8(u, a);
                }
                const float inv = 1.0f / fmaxf((float)(end - beg), 1.0f);
                ushort4 lo4, hi4;
                lo4.x = f2bf(a[0] * inv); lo4.y = f2bf(a[1] * inv);
                lo4.z = f2bf(a[2] * inv); lo4.w = f2bf(a[3] * inv);
                hi4.x = f2bf(a[4] * inv); hi4.y = f2bf(a[5] * inv);
                hi4.z = f2bf(a[6] * inv); hi4.w = f2bf(a[7] * inv);
                *reinterpret_cast<ushort4*>(dp)     = lo4;
                *reinterpret_cast<ushort4*>(dp + 4) = hi4;
            } else {
                const ushort4 z = {0, 0, 0, 0};
                *reinterpret_cast<ushort4*>(dp)     = z;
                *reinterpret_cast<ushort4*>(dp + 4) = z;
            }
        }
    }
    __syncthreads();

    const int lane = tid & 63;
    const int wave = tid >> 6;
    const int lr = lane & 15;
    const int q  = lane >> 4;
    f32x4 acc[4];
#pragma unroll
    for (int t = 0; t < 4; ++t) {
        const float b = bias[t * 16 + lr];
        acc[t] = (f32x4){b, b, b, b};
    }
    const unsigned short* Arow = &A_s[(wave * 16 + lr) * STR + q * 8];
    const unsigned short* Brow = whi + (size_t)lr * K + q * 8;
    for (int s = 0; s < nSteps; ++s) {
        const bf16x8 af = *reinterpret_cast<const bf16x8*>(Arow + s * 32);
#pragma unroll
        for (int t = 0; t < 4; ++t) {
            const bf16x8 bh = *reinterpret_cast<const bf16x8*>(
                Brow + (size_t)t * 16 * K + s * 32);
            acc[t] = __builtin_amdgcn_mfma_f32_16x16x32_bf16(af, bh, acc[t], 0, 0, 0);
        }
    }

    for (int reg = 0; reg < 4; ++reg) {
        const int n = nodeBase + wave * 16 + q * 4 + reg;
        if (n >= N) break;
#pragma unroll
        for (int t = 0; t < 4; ++t)
            houtb[(size_t)n * 64 + t * 16 + lr] = f2bf(fmaxf(acc[t][reg], 0.0f));
    }
}

// ---------- head: per-graph count via binary search over sorted batch ----------

__device__ inline int lower_bound_batch(const int* __restrict__ batch, int N, int key) {
    int lo = 0, hi = N;
    while (lo < hi) {
        const int mid = (lo + hi) >> 1;
        if (batch[mid] < key) lo = mid + 1; else hi = mid;
    }
    return lo;
}

__global__ void final_kernel(const float* __restrict__ pool_sum,
                             const int* __restrict__ batch,
                             const float* __restrict__ W_lin,
                             const float* __restrict__ b_lin,
                             float* __restrict__ out, int G, int N) {
    int t = blockIdx.x * blockDim.x + threadIdx.x;
    if (t >= G * 2) return;
    int g = t >> 1, o = t & 1;
    const int c0 = lower_bound_batch(batch, N, g);
    const int c1 = lower_bound_batch(batch, N, g + 1);
    float inv = 1.0f / fmaxf((float)(c1 - c0), 1.0f);
    float acc = b_lin[o];
#pragma unroll
    for (int c = 0; c < 64; ++c)
        acc = fmaf(pool_sum[(size_t)g * 64 + c] * inv, W_lin[o * 64 + c], acc);
    out[t] = acc;
}

extern "C" void kernel_launch(void* const* d_in, const int* in_sizes, int n_in,
                              void* d_out, int out_size, void* d_ws, size_t ws_size,
                              hipStream_t stream) {
    const float* x     = (const float*)d_in[0];
    const int*   ei    = (const int*)d_in[1];
    const int*   batch = (const int*)d_in[2];
    const float* W1_l  = (const float*)d_in[3];
    const float* b1    = (const float*)d_in[4];
    const float* W1_r  = (const float*)d_in[5];
    const float* W2_l  = (const float*)d_in[6];
    const float* b2    = (const float*)d_in[7];
    const float* W2_r  = (const float*)d_in[8];
    const float* W_lin = (const float*)d_in[9];
    const float* b_lin = (const float*)d_in[10];

    const int N = in_sizes[0] / 32;
    const int E = in_sizes[1] / 2;
    const int G = out_size / 2;
    const int* src = ei;
    const int* dst = ei + E;
    const int NB = (N + BNODES - 1) >> BSHIFT;   // 782 for N=200000

    char* p = (char*)d_ws;
    auto carve = [&](size_t bytes) -> void* {
        void* r = (void*)p;
        p += (bytes + (WS_ALIGN - 1)) / WS_ALIGN * WS_ALIGN;
        return r;
    };
    int*            bucketCursor = (int*)carve((size_t)MAXNB * 4);
    unsigned*       bucketData   = (unsigned*)carve((size_t)NB * BCAP * 4);
    int*            offs         = (int*)carve((size_t)N * 4);
    int*            offe         = (int*)carve((size_t)N * 4);
    int*            csr_src      = (int*)carve((size_t)NB * BCAP * 4);
    unsigned short* xb           = (unsigned short*)carve((size_t)N * 32 * 2);
    unsigned short* aggb         = (unsigned short*)carve((size_t)N * 64 * 2);
    unsigned short* h1b          = (unsigned short*)carve((size_t)N * 64 * 2);
    unsigned short* whi1         = (unsigned short*)carve(64 * 64 * 2);
    unsigned short* whi2         = (unsigned short*)carve(64 * 128 * 2);
    float*          pool         = (float*)carve((size_t)G * 64 * 4);
    float*          out          = (float*)d_out;

    const int TB = 256;
    const int total4 = N * 32 / 4;
    prep_kernel<<<(total4 + TB - 1) / TB, TB, 0, stream>>>(
        x, xb, W1_l, W1_r, W2_l, W2_r, whi1, whi2, bucketCursor, pool,
        N, NB, G, total4);
    bucket_scatter_kernel<<<(E + EPB - 1) / EPB, TB, 0, stream>>>(src, dst, bucketCursor,
                                                                  bucketData, E, NB);
    csr_build_kernel<<<NB, TB, 0, stream>>>(bucketData, bucketCursor, offs, offe, csr_src, N);

    // layer 1: fused gather-mean(xb) + MFMA 32->64 + relu -> h1b (bf16)
    fused_agg_mfma_kernel<32, false><<<(N + 63) / 64, TB, 0, stream>>>(
        xb, whi1, b1, csr_src, offs, offe, h1b, nullptr, nullptr, N, 2);

    // layer 2 (split): gather-mean(h1b) -> aggb, then MFMA + relu + pool
    agg_bf16_kernel<64><<<((size_t)N * 8 + TB - 1) / TB, TB, 0, stream>>>(
        h1b, csr_src, offs, offe, aggb, N);
    mfma_dense_kernel<64, true><<<(N + 63) / 64, TB, 0, stream>>>(
        aggb, h1b, whi2, b2, nullptr, batch, pool, N, 4);

    final_kernel<<<(G * 2 + TB - 1) / TB, TB, 0, stream>>>(pool, batch, W_lin, b_lin,
                                                           out, G, N);
}

// Round 10
// 337.030 us; speedup vs baseline: 1.0737x; 1.0737x over previous
//
#include <hip/hip_runtime.h>
#include <hip/hip_bf16.h>

// JetGNN: 2-layer SAGEConv(mean) + ReLU + global_mean_pool + Linear(64->2)
// R1-R21: scan/CSR/pool/agg/MFMA ladder (see git log). 355.7us R21.
// R22-R28: fusion arc; gather pinned ~2 TB/s in fused vs 3.46 split.
// R29: pool de-atomicized (LDS + boundary atomics): WRITE 21.9->1.76MB,
//      fused2 115->99us, total 344.6 (best).
// R30: layer-2 re-split -- REGRESSION 361.9 (agg2+mfma2=116 > fused2 99).
//      Profile: fused1=65.8 top; per-edge rate invariant ~50 G-edge/s in
//      barrier-free kernels, 32 in fused2 => block barrier prevents wave
//      retire+backfill (R24 showed resident blocks don't substitute).
// R31: wave-autonomous fusion. Each wave owns its 16-row tile: stage self,
//      gather (8 lanes/node, 1 txn/row), s_waitcnt lgkmcnt(0) wave-sync
//      (no block barrier), MFMA, epilogue. fused1: ZERO barriers -> waves
//      retire like the split kernel. fused2: barriers only around pool
//      flush; poolLds 64->16 rows (graphs ~50 nodes; r>=16 -> direct
//      global atomic fallback) -> LDS 21568, 7 blocks/CU.

#define WS_ALIGN 64
#define EPB 4096          // edges per block in bucket_scatter (256 thr x 16)
#define BSHIFT 8          // 256 nodes per bucket
#define BNODES 256
#define BCAP 6144         // region capacity (mean 4096, sd 64, +32 sigma)
#define MAXNB 1024

typedef short bf16x8 __attribute__((ext_vector_type(8)));
typedef float f32x4 __attribute__((ext_vector_type(4)));

__device__ inline unsigned short f2bf(float f) {   // RNE f32->bf16 (finite inputs)
    unsigned u = __float_as_uint(f);
    return (unsigned short)((u + 0x7fffu + ((u >> 16) & 1u)) >> 16);
}

__device__ inline void acc8(const uint4 u, float* a) {  // 8 bf16 -> fp32 accumulate
    a[0] += __uint_as_float(u.x << 16);
    a[1] += __uint_as_float(u.x & 0xffff0000u);
    a[2] += __uint_as_float(u.y << 16);
    a[3] += __uint_as_float(u.y & 0xffff0000u);
    a[4] += __uint_as_float(u.z << 16);
    a[5] += __uint_as_float(u.z & 0xffff0000u);
    a[6] += __uint_as_float(u.w << 16);
    a[7] += __uint_as_float(u.w & 0xffff0000u);
}

// ---------- prep: x->bf16 cvt + weight prepack + cursors + pool zero ----------

__global__ void prep_kernel(const float* __restrict__ x, unsigned short* __restrict__ xb,
                            const float* __restrict__ W1_l, const float* __restrict__ W1_r,
                            const float* __restrict__ W2_l, const float* __restrict__ W2_r,
                            unsigned short* __restrict__ whi1, unsigned short* __restrict__ whi2,
                            int* __restrict__ bucketCursor, float* __restrict__ pool,
                            int N, int NB, int G, int total4) {
    const int gid = blockIdx.x * blockDim.x + threadIdx.x;
    if (gid < total4) {
        const float4 v = reinterpret_cast<const float4*>(x)[gid];
        ushort4 o;
        o.x = f2bf(v.x); o.y = f2bf(v.y); o.z = f2bf(v.z); o.w = f2bf(v.w);
        reinterpret_cast<ushort4*>(xb)[gid] = o;
    }
    if (gid < NB) bucketCursor[gid] = gid * BCAP;
    if (gid < G * 64) pool[gid] = 0.0f;     // consumed only by fused2 (later launch)
    if (gid < 64 * 64) {        // whi1: rows [o][k], K=64
        const int o = gid >> 6, k = gid & 63;
        const float v = (k < 32) ? W1_l[o * 32 + k] : W1_r[o * 32 + (k - 32)];
        whi1[gid] = f2bf(v);
    }
    if (gid < 64 * 128) {       // whi2: rows [o][k], K=128
        const int o = gid >> 7, k = gid & 127;
        const float v = (k < 64) ? W2_l[o * 64 + k] : W2_r[o * 64 + (k - 64)];
        whi2[gid] = f2bf(v);
    }
}

// ---------- bucket scatter: edges -> fixed-capacity bucket regions ----------

__global__ __launch_bounds__(256) void bucket_scatter_kernel(const int* __restrict__ src,
                                                             const int* __restrict__ dst,
                                                             int* __restrict__ bucketCursor,
                                                             unsigned* __restrict__ bucketData,
                                                             int E, int NB) {
    __shared__ int hist[MAXNB];
    __shared__ int cur[MAXNB];
    const int t = threadIdx.x;
    for (int i = t; i < MAXNB; i += 256) hist[i] = 0;
    __syncthreads();
    const int eBase = blockIdx.x * EPB + t;
    int s[16], b[16], dl[16];
#pragma unroll
    for (int j = 0; j < 16; ++j) {
        int e = eBase + j * 256;
        if (e < E) {
            int d = dst[e];
            s[j]  = src[e];
            b[j]  = d >> BSHIFT;
            dl[j] = d & (BNODES - 1);
            atomicAdd(&hist[b[j]], 1);
        } else {
            b[j] = -1;
        }
    }
    __syncthreads();
    for (int bb = t; bb < NB; bb += 256)
        if (hist[bb] > 0) cur[bb] = atomicAdd(&bucketCursor[bb], hist[bb]);
    __syncthreads();
#pragma unroll
    for (int j = 0; j < 16; ++j) {
        if (b[j] >= 0) {
            int pos = atomicAdd(&cur[b[j]], 1);
            if (pos < (b[j] + 1) * BCAP)     // overflow guard (statistically never)
                bucketData[pos] = ((unsigned)s[j] << BSHIFT) | (unsigned)dl[j];
        }
    }
}

// one block per bucket (256 nodes): LDS deg hist over its region -> scan ->
// offs/offe; scatter pass into the region (dense, single-XCD write-back)
__global__ __launch_bounds__(256) void csr_build_kernel(const unsigned* __restrict__ bucketData,
                                                        const int* __restrict__ bucketCursor,
                                                        int* __restrict__ offs,
                                                        int* __restrict__ offe,
                                                        int* __restrict__ csr_src,
                                                        int N) {
    __shared__ int cnt[BNODES];
    __shared__ int sscan[BNODES];
    __shared__ int cur[BNODES];
    const int t   = threadIdx.x;
    const int bkt = blockIdx.x;
    const int nodeBase = bkt << BSHIFT;
    const int regionBase = bkt * BCAP;
    const int count = min(bucketCursor[bkt] - regionBase, BCAP);
    cnt[t] = 0;
    __syncthreads();
    for (int k = regionBase + t; k < regionBase + count; k += 256)
        atomicAdd(&cnt[bucketData[k] & (BNODES - 1)], 1);
    __syncthreads();
    int v0 = cnt[t];
    sscan[t] = v0;
    __syncthreads();
    for (int off = 1; off < 256; off <<= 1) {
        int v = (t >= off) ? sscan[t - off] : 0;
        __syncthreads();
        sscan[t] += v;
        __syncthreads();
    }
    const int excl = sscan[t] - v0;
    cur[t] = excl;
    const int node = nodeBase + t;
    if (node < N) {
        offs[node] = regionBase + excl;
        offe[node] = regionBase + excl + v0;
    }
    __syncthreads();
    for (int k = regionBase + t; k < regionBase + count; k += 256) {
        const unsigned v = bucketData[k];
        const int d = (int)(v & (BNODES - 1));
        const int pos = regionBase + atomicAdd(&cur[d], 1);
        csr_src[pos] = (int)(v >> BSHIFT);
    }
}

// ---------- wave-autonomous fused gather-mean + MFMA + relu (+pool) ----------
// Per block: 64 nodes = 4 waves x 16-row tiles. Each wave: stage self rows,
// gather its rows (D8 lanes/node, 1 uint4/edge), wave-sync via lgkmcnt(0)
// (NO block barrier), MFMA vs B (global, L2-hot), epilogue. POOL: LDS pool
// accumulate (16 rows; r>=16 -> direct global atomic) + one flush barrier.

template <int DIN, bool POOL>
__launch_bounds__(256)
__global__ void fused_agg_mfma_kernel(const unsigned short* __restrict__ featb,
                                      const unsigned short* __restrict__ whi,
                                      const float* __restrict__ bias,
                                      const int* __restrict__ csr_src,
                                      const int* __restrict__ offs,
                                      const int* __restrict__ offe,
                                      unsigned short* __restrict__ houtb,
                                      const int* __restrict__ batch,
                                      float* __restrict__ pool_sum,
                                      int N, int nSteps) {
    constexpr int K     = 2 * DIN;    // 64 / 128
    constexpr int STR   = K + 8;      // 72 / 136 ushorts, rows 16B-aligned
    constexpr int D8    = DIN / 8;    // uint4 per feature row (4 / 8)
    constexpr int NPW   = 64 / D8;    // nodes gathered per wave pass (16 / 8)
    constexpr int NPASS = 16 / NPW;   // passes to cover wave's 16 rows (1 / 2)
    __shared__ unsigned short A_s[64 * STR];
    __shared__ float poolLds[POOL ? 16 * 65 : 1];   // [graph-row][ch]
    const int tid  = threadIdx.x;
    const int lane = tid & 63;
    const int wave = tid >> 6;
    const int nodeBase = blockIdx.x * 64;
    const int rowBase  = wave * 16;           // wave-owned A_s rows

    if (POOL) {
        for (int i = tid; i < 16 * 65; i += 256) poolLds[i] = 0.0f;
        __syncthreads();   // cheap: pre-gather, all waves arrive together
    }

    // ---- per-wave: self features into k [DIN, 2*DIN) of rows [rowBase,+16) ----
    for (int i = lane; i < 16 * D8; i += 64) {
        const int row = rowBase + i / D8, q = i % D8;
        const int n = min(nodeBase + row, N - 1);
        const uint4 u = *reinterpret_cast<const uint4*>(featb + (size_t)n * DIN + q * 8);
        *reinterpret_cast<uint4*>(&A_s[row * STR + DIN + q * 8]) = u;
    }

    // ---- per-wave: gather-mean into k [0, DIN): D8 lanes/node, 1 uint4/edge ----
    {
        const int part = lane % D8;
        const uint4* base = reinterpret_cast<const uint4*>(featb);
#pragma unroll
        for (int pass = 0; pass < NPASS; ++pass) {
            const int row = rowBase + pass * NPW + lane / D8;
            const int n = nodeBase + row;
            unsigned short* dp = &A_s[row * STR + part * 8];
            if (n < N) {
                const int beg = offs[n];
                const int end = offe[n];
                float a[8] = {0.f, 0.f, 0.f, 0.f, 0.f, 0.f, 0.f, 0.f};
                int k = beg;
                for (; k + 8 <= end; k += 8) {       // 8 uint4 in flight
                    int s[8];
#pragma unroll
                    for (int j = 0; j < 8; ++j) s[j] = csr_src[k + j];
                    uint4 u[8];
#pragma unroll
                    for (int j = 0; j < 8; ++j) u[j] = base[(size_t)s[j] * D8 + part];
#pragma unroll
                    for (int j = 0; j < 8; ++j) acc8(u[j], a);
                }
                for (; k + 4 <= end; k += 4) {
                    const int s0 = csr_src[k + 0];
                    const int s1 = csr_src[k + 1];
                    const int s2 = csr_src[k + 2];
                    const int s3 = csr_src[k + 3];
                    const uint4 u0 = base[(size_t)s0 * D8 + part];
                    const uint4 u1 = base[(size_t)s1 * D8 + part];
                    const uint4 u2 = base[(size_t)s2 * D8 + part];
                    const uint4 u3 = base[(size_t)s3 * D8 + part];
                    acc8(u0, a); acc8(u1, a); acc8(u2, a); acc8(u3, a);
                }
                for (; k < end; ++k) {
                    const uint4 u = base[(size_t)csr_src[k] * D8 + part];
                    acc8(u, a);
                }
                const float inv = 1.0f / fmaxf((float)(end - beg), 1.0f);
                ushort4 lo4, hi4;
                lo4.x = f2bf(a[0] * inv); lo4.y = f2bf(a[1] * inv);
                lo4.z = f2bf(a[2] * inv); lo4.w = f2bf(a[3] * inv);
                hi4.x = f2bf(a[4] * inv); hi4.y = f2bf(a[5] * inv);
                hi4.z = f2bf(a[6] * inv); hi4.w = f2bf(a[7] * inv);
                *reinterpret_cast<ushort4*>(dp)     = lo4;
                *reinterpret_cast<ushort4*>(dp + 4) = hi4;
            } else {
                const ushort4 z = {0, 0, 0, 0};
                *reinterpret_cast<ushort4*>(dp)     = z;
                *reinterpret_cast<ushort4*>(dp + 4) = z;
            }
        }
    }

    // wave-sync: drain this wave's LDS writes before its ds_reads (no block
    // barrier -- rows are wave-private). sched_barrier pins ordering (rule 18).
    asm volatile("s_waitcnt lgkmcnt(0)" ::: "memory");
    __builtin_amdgcn_sched_barrier(0);

    const int lr = lane & 15;        // A: m (node); B: n (out); D: col (out)
    const int q  = lane >> 4;        // frag k-quad; D row group
    f32x4 acc[4];
#pragma unroll
    for (int t = 0; t < 4; ++t) {
        const float b = bias[t * 16 + lr];
        acc[t] = (f32x4){b, b, b, b};
    }
    const unsigned short* Arow = &A_s[(rowBase + lr) * STR + q * 8];
    const unsigned short* Brow = whi + (size_t)lr * K + q * 8;   // + t*16*K + s*32
    for (int s = 0; s < nSteps; ++s) {    // runtime: no full unroll (R11)
        const bf16x8 af = *reinterpret_cast<const bf16x8*>(Arow + s * 32);
#pragma unroll
        for (int t = 0; t < 4; ++t) {
            const bf16x8 bh = *reinterpret_cast<const bf16x8*>(
                Brow + (size_t)t * 16 * K + s * 32);
            acc[t] = __builtin_amdgcn_mfma_f32_16x16x32_bf16(af, bh, acc[t], 0, 0, 0);
        }
    }

    // D layout: row(node local 16) = q*4 + reg, col(out) = t*16 + lr
    if (POOL) {
        const int g0 = batch[nodeBase];
        float ag[4] = {0.f, 0.f, 0.f, 0.f};
        int gcur = -1;
        auto flush_run = [&](int g) {
            const int r = g - g0;
            if (r < 16) {
#pragma unroll
                for (int t = 0; t < 4; ++t)
                    atomicAdd(&poolLds[r * 65 + t * 16 + lr], ag[t]);
            } else {       // statistically never (graphs avg ~50 nodes)
#pragma unroll
                for (int t = 0; t < 4; ++t)
                    atomicAdd(&pool_sum[(size_t)g * 64 + t * 16 + lr], ag[t]);
            }
        };
        for (int reg = 0; reg < 4; ++reg) {
            const int n = nodeBase + rowBase + q * 4 + reg;
            if (n >= N) break;
            const int g = batch[n];              // sorted
            if (g != gcur) {
                if (gcur >= 0) flush_run(gcur);
                gcur = g;
                ag[0] = ag[1] = ag[2] = ag[3] = 0.f;
            }
#pragma unroll
            for (int t = 0; t < 4; ++t)
                ag[t] += fmaxf(acc[t][reg], 0.0f);
        }
        if (gcur >= 0) flush_run(gcur);
        __syncthreads();
        // flush: interior rows sole-writer -> plain store (pool pre-zeroed);
        // boundary rows (r==0, r==S-1) -> global atomicAdd.
        const int glast = batch[min(nodeBase + 63, N - 1)];
        const int S = min(glast - g0 + 1, 16);
        for (int i = tid; i < S * 64; i += 256) {
            const int r = i >> 6, c = i & 63;
            const float v = poolLds[r * 65 + c];
            float* dstp = &pool_sum[(size_t)(g0 + r) * 64 + c];
            if (r == 0 || r == S - 1) atomicAdd(dstp, v);
            else *dstp = v;
        }
    } else {
        for (int reg = 0; reg < 4; ++reg) {
            const int n = nodeBase + rowBase + q * 4 + reg;
            if (n >= N) break;
#pragma unroll
            for (int t = 0; t < 4; ++t)
                houtb[(size_t)n * 64 + t * 16 + lr] = f2bf(fmaxf(acc[t][reg], 0.0f));
        }
    }
}

// ---------- head: per-graph count via binary search over sorted batch ----------

__device__ inline int lower_bound_batch(const int* __restrict__ batch, int N, int key) {
    int lo = 0, hi = N;
    while (lo < hi) {
        const int mid = (lo + hi) >> 1;
        if (batch[mid] < key) lo = mid + 1; else hi = mid;
    }
    return lo;
}

__global__ void final_kernel(const float* __restrict__ pool_sum,
                             const int* __restrict__ batch,
                             const float* __restrict__ W_lin,
                             const float* __restrict__ b_lin,
                             float* __restrict__ out, int G, int N) {
    int t = blockIdx.x * blockDim.x + threadIdx.x;
    if (t >= G * 2) return;
    int g = t >> 1, o = t & 1;
    const int c0 = lower_bound_batch(batch, N, g);
    const int c1 = lower_bound_batch(batch, N, g + 1);
    float inv = 1.0f / fmaxf((float)(c1 - c0), 1.0f);
    float acc = b_lin[o];
#pragma unroll
    for (int c = 0; c < 64; ++c)
        acc = fmaf(pool_sum[(size_t)g * 64 + c] * inv, W_lin[o * 64 + c], acc);
    out[t] = acc;
}

extern "C" void kernel_launch(void* const* d_in, const int* in_sizes, int n_in,
                              void* d_out, int out_size, void* d_ws, size_t ws_size,
                              hipStream_t stream) {
    const float* x     = (const float*)d_in[0];
    const int*   ei    = (const int*)d_in[1];
    const int*   batch = (const int*)d_in[2];
    const float* W1_l  = (const float*)d_in[3];
    const float* b1    = (const float*)d_in[4];
    const float* W1_r  = (const float*)d_in[5];
    const float* W2_l  = (const float*)d_in[6];
    const float* b2    = (const float*)d_in[7];
    const float* W2_r  = (const float*)d_in[8];
    const float* W_lin = (const float*)d_in[9];
    const float* b_lin = (const float*)d_in[10];

    const int N = in_sizes[0] / 32;
    const int E = in_sizes[1] / 2;
    const int G = out_size / 2;
    const int* src = ei;
    const int* dst = ei + E;
    const int NB = (N + BNODES - 1) >> BSHIFT;   // 782 for N=200000

    char* p = (char*)d_ws;
    auto carve = [&](size_t bytes) -> void* {
        void* r = (void*)p;
        p += (bytes + (WS_ALIGN - 1)) / WS_ALIGN * WS_ALIGN;
        return r;
    };
    int*            bucketCursor = (int*)carve((size_t)MAXNB * 4);
    unsigned*       bucketData   = (unsigned*)carve((size_t)NB * BCAP * 4);
    int*            offs         = (int*)carve((size_t)N * 4);
    int*            offe         = (int*)carve((size_t)N * 4);
    int*            csr_src      = (int*)carve((size_t)NB * BCAP * 4);
    unsigned short* xb           = (unsigned short*)carve((size_t)N * 32 * 2);
    unsigned short* h1b          = (unsigned short*)carve((size_t)N * 64 * 2);
    unsigned short* whi1         = (unsigned short*)carve(64 * 64 * 2);
    unsigned short* whi2         = (unsigned short*)carve(64 * 128 * 2);
    float*          pool         = (float*)carve((size_t)G * 64 * 4);
    float*          out          = (float*)d_out;

    const int TB = 256;
    const int total4 = N * 32 / 4;
    prep_kernel<<<(total4 + TB - 1) / TB, TB, 0, stream>>>(
        x, xb, W1_l, W1_r, W2_l, W2_r, whi1, whi2, bucketCursor, pool,
        N, NB, G, total4);
    bucket_scatter_kernel<<<(E + EPB - 1) / EPB, TB, 0, stream>>>(src, dst, bucketCursor,
                                                                  bucketData, E, NB);
    csr_build_kernel<<<NB, TB, 0, stream>>>(bucketData, bucketCursor, offs, offe, csr_src, N);

    // layer 1: fused gather-mean(xb) + MFMA 32->64 + relu -> h1b (bf16)
    fused_agg_mfma_kernel<32, false><<<(N + 63) / 64, TB, 0, stream>>>(
        xb, whi1, b1, csr_src, offs, offe, h1b, nullptr, nullptr, N, 2);

    // layer 2: fused gather-mean(h1b) + MFMA 64->64 + relu + pool
    fused_agg_mfma_kernel<64, true><<<(N + 63) / 64, TB, 0, stream>>>(
        h1b, whi2, b2, csr_src, offs, offe, nullptr, batch, pool, N, 4);

    final_kernel<<<(G * 2 + TB - 1) / TB, TB, 0, stream>>>(pool, batch, W_lin, b_lin,
                                                           out, G, N);
}